// Round 1
// baseline (1144.615 us; speedup 1.0000x reference)
//
#include <hip/hip_runtime.h>

#define V_N 30522
#define A_N 2
#define H_N 128
#define O_N 16
#define B_N 8
#define D_N 256
#define NNZ_N 250000
#define M_N (B_N * D_N)  // 2048

#define BM 64
#define BK 32
#define KSPLIT 32
#define KC ((V_N + KSPLIT - 1) / KSPLIT)  // 954

// ---------------- SPMM: h_sum[r,:] += vals * W[a][col,:] (atomic scatter) ---------------
__global__ __launch_bounds__(256) void spmm_atomic(const int* __restrict__ rows,
                                                   const int* __restrict__ cols,
                                                   const float* __restrict__ vals,
                                                   const float* __restrict__ W,
                                                   float* __restrict__ h_sum) {
    long long idx = (long long)blockIdx.x * blockDim.x + threadIdx.x;
    int n = (int)(idx >> 5);   // nnz index across both adjacencies
    int c = (int)(idx & 31);   // float4 chunk of the 128-wide row
    if (n >= A_N * NNZ_N) return;
    int a = n / NNZ_N;
    int r = rows[n];
    int col = cols[n];
    float v = vals[n];
    const float4 w = *reinterpret_cast<const float4*>(
        W + ((long long)(a * V_N + col)) * H_N + c * 4);
    float* dst = h_sum + (long long)r * H_N + c * 4;
    atomicAdd(dst + 0, v * w.x);
    atomicAdd(dst + 1, v * w.y);
    atomicAdd(dst + 2, v * w.z);
    atomicAdd(dst + 3, v * w.w);
}

// ---------------- GEMM: fused[2048,128] += X[2048,V] @ h_sum[V,128], split-K ------------
__global__ __launch_bounds__(256) void gemm_split(const float* __restrict__ X,
                                                  const float* __restrict__ Hs,
                                                  float* __restrict__ fused) {
    __shared__ float xs[BM][BK + 1];
    __shared__ float hs[BK][H_N];
    const int mtile = blockIdx.x;   // 0..31
    const int ks = blockIdx.y;      // 0..KSPLIT-1
    const int tid = threadIdx.x;
    const int tx = tid & 31;        // col group: cols tx*4 .. tx*4+3
    const int ty = tid >> 5;        // 0..7 : rows ty*8 .. ty*8+7
    const int k0 = ks * KC;
    const int k1 = min(V_N, k0 + KC);
    const int row0 = mtile * BM;

    float acc[8][4] = {};

    for (int kb = k0; kb < k1; kb += BK) {
        // stage X tile: 64 rows x 32 cols
        {
            int lane8 = tid & 7;
            int r = tid >> 3;  // 0..31
            int kcol = kb + lane8 * 4;
            for (int rr = r; rr < BM; rr += 32) {
                float4 xv = make_float4(0.f, 0.f, 0.f, 0.f);
                if (kcol + 3 < k1) {
                    xv = *reinterpret_cast<const float4*>(
                        X + (long long)(row0 + rr) * V_N + kcol);
                } else {
                    float tmp[4] = {0.f, 0.f, 0.f, 0.f};
                    for (int j = 0; j < 4; ++j)
                        if (kcol + j < k1)
                            tmp[j] = X[(long long)(row0 + rr) * V_N + kcol + j];
                    xv = make_float4(tmp[0], tmp[1], tmp[2], tmp[3]);
                }
                xs[rr][lane8 * 4 + 0] = xv.x;
                xs[rr][lane8 * 4 + 1] = xv.y;
                xs[rr][lane8 * 4 + 2] = xv.z;
                xs[rr][lane8 * 4 + 3] = xv.w;
            }
        }
        // stage H tile: 32 rows x 128 cols
        {
            int cc = tid & 31;
            int rr = tid >> 5;  // 0..7
            for (int r2 = rr; r2 < BK; r2 += 8) {
                int krow = kb + r2;
                float4 hv = make_float4(0.f, 0.f, 0.f, 0.f);
                if (krow < k1)
                    hv = *reinterpret_cast<const float4*>(
                        Hs + (long long)krow * H_N + cc * 4);
                *reinterpret_cast<float4*>(&hs[r2][cc * 4]) = hv;
            }
        }
        __syncthreads();
#pragma unroll
        for (int kk = 0; kk < BK; ++kk) {
            float4 hv = *reinterpret_cast<const float4*>(&hs[kk][tx * 4]);
#pragma unroll
            for (int i = 0; i < 8; ++i) {
                float xv = xs[ty * 8 + i][kk];
                acc[i][0] += xv * hv.x;
                acc[i][1] += xv * hv.y;
                acc[i][2] += xv * hv.z;
                acc[i][3] += xv * hv.w;
            }
        }
        __syncthreads();
    }

#pragma unroll
    for (int i = 0; i < 8; ++i) {
        int row = row0 + ty * 8 + i;
        float* dst = fused + (long long)row * H_N + tx * 4;
        atomicAdd(dst + 0, acc[i][0]);
        atomicAdd(dst + 1, acc[i][1]);
        atomicAdd(dst + 2, acc[i][2]);
        atomicAdd(dst + 3, acc[i][3]);
    }
}

// ---------------- FC epilogue: out[2048,16] = fused[2048,128] @ fcW[128,16] + b ---------
__global__ __launch_bounds__(256) void fc_kernel(const float* __restrict__ fused,
                                                 const float* __restrict__ fcW,
                                                 const float* __restrict__ fcb,
                                                 float* __restrict__ out) {
    int idx = blockIdx.x * blockDim.x + threadIdx.x;  // row*16 + o
    if (idx >= M_N * O_N) return;
    int row = idx >> 4;
    int o = idx & 15;
    float s = fcb[o];
    const float* f = fused + (long long)row * H_N;
#pragma unroll
    for (int h = 0; h < H_N; ++h) s += f[h] * fcW[h * O_N + o];
    out[idx] = s;
}

extern "C" void kernel_launch(void* const* d_in, const int* in_sizes, int n_in,
                              void* d_out, int out_size, void* d_ws, size_t ws_size,
                              hipStream_t stream) {
    const float* x   = (const float*)d_in[0];
    const int* rows  = (const int*)d_in[1];
    const int* cols  = (const int*)d_in[2];
    const float* vals= (const float*)d_in[3];
    const float* W   = (const float*)d_in[4];
    const float* fcW = (const float*)d_in[5];
    const float* fcb = (const float*)d_in[6];
    float* out = (float*)d_out;

    float* h_sum = (float*)d_ws;                       // V*H f32
    float* fused = h_sum + (size_t)V_N * H_N;          // M*H f32

    size_t zero_bytes = ((size_t)V_N * H_N + (size_t)M_N * H_N) * sizeof(float);
    hipMemsetAsync(d_ws, 0, zero_bytes, stream);

    long long nnz_threads = (long long)A_N * NNZ_N * 32;
    int spmm_blocks = (int)((nnz_threads + 255) / 256);
    spmm_atomic<<<spmm_blocks, 256, 0, stream>>>(rows, cols, vals, W, h_sum);

    dim3 g(M_N / BM, KSPLIT);
    gemm_split<<<g, 256, 0, stream>>>(x, h_sum, fused);

    fc_kernel<<<(M_N * O_N + 255) / 256, 256, 0, stream>>>(fused, fcW, fcb, out);
}

// Round 2
// 470.710 us; speedup vs baseline: 2.4317x; 2.4317x over previous
//
#include <hip/hip_runtime.h>

#define V_N 30522
#define A_N 2
#define H_N 128
#define O_N 16
#define B_N 8
#define D_N 256
#define NNZ_N 250000
#define NNZ_T (A_N * NNZ_N)  // 500000
#define M_N (B_N * D_N)      // 2048

#define BM 64
#define BK 32
#define KSPLIT 32
#define KC ((V_N + KSPLIT - 1) / KSPLIT)  // 954

// ---------------- Step 1: histogram of row indices ----------------
__global__ __launch_bounds__(256) void hist_kernel(const int* __restrict__ rows,
                                                   int* __restrict__ count) {
    int n = blockIdx.x * blockDim.x + threadIdx.x;
    if (n >= NNZ_T) return;
    atomicAdd(&count[rows[n]], 1);
}

// ---------------- Step 2: exclusive prefix scan (single block) ----------------
__global__ __launch_bounds__(1024) void scan_kernel(const int* __restrict__ count,
                                                    int* __restrict__ row_start,
                                                    int* __restrict__ cursor) {
    __shared__ int sdata[1024];
    __shared__ int carry;
    if (threadIdx.x == 0) carry = 0;
    __syncthreads();
    for (int base = 0; base < V_N; base += 1024) {
        int i = base + threadIdx.x;
        int v = (i < V_N) ? count[i] : 0;
        sdata[threadIdx.x] = v;
        __syncthreads();
        for (int off = 1; off < 1024; off <<= 1) {
            int t = (threadIdx.x >= off) ? sdata[threadIdx.x - off] : 0;
            __syncthreads();
            sdata[threadIdx.x] += t;
            __syncthreads();
        }
        int exc = sdata[threadIdx.x] - v + carry;
        if (i < V_N) { row_start[i] = exc; cursor[i] = exc; }
        __syncthreads();
        if (threadIdx.x == 1023) carry += sdata[1023];
        __syncthreads();
    }
    if (threadIdx.x == 0) row_start[V_N] = carry;
}

// ---------------- Step 3: scatter nnz into row-sorted order ----------------
__global__ __launch_bounds__(256) void scatter_kernel(const int* __restrict__ rows,
                                                      const int* __restrict__ cols,
                                                      const float* __restrict__ vals,
                                                      int* __restrict__ cursor,
                                                      int* __restrict__ sorted_colp,
                                                      float* __restrict__ sorted_val) {
    int n = blockIdx.x * blockDim.x + threadIdx.x;
    if (n >= NNZ_T) return;
    int a = n / NNZ_N;
    int r = rows[n];
    int pos = atomicAdd(&cursor[r], 1);
    sorted_colp[pos] = a * V_N + cols[n];
    sorted_val[pos] = vals[n];
}

// ---------------- Step 4: segmented accumulate, no atomics ----------------
// thread = row * 32 + chunk; each thread owns a float4 column chunk of h_sum[row]
__global__ __launch_bounds__(256) void accum_kernel(const int* __restrict__ row_start,
                                                    const int* __restrict__ sorted_colp,
                                                    const float* __restrict__ sorted_val,
                                                    const float* __restrict__ W,
                                                    float* __restrict__ h_sum) {
    long long gid = (long long)blockIdx.x * blockDim.x + threadIdx.x;
    if (gid >= (long long)V_N * 32) return;
    int row = (int)(gid >> 5);
    int chunk = (int)(gid & 31);
    int s = row_start[row];
    int e = row_start[row + 1];
    float4 acc = make_float4(0.f, 0.f, 0.f, 0.f);
    for (int i = s; i < e; ++i) {
        int cp = sorted_colp[i];
        float v = sorted_val[i];
        const float4 w = *reinterpret_cast<const float4*>(
            W + (long long)cp * H_N + chunk * 4);
        acc.x += v * w.x;
        acc.y += v * w.y;
        acc.z += v * w.z;
        acc.w += v * w.w;
    }
    *reinterpret_cast<float4*>(h_sum + (long long)row * H_N + chunk * 4) = acc;
}

// ---------------- GEMM: fused[2048,128] += X[2048,V] @ h_sum[V,128], split-K ------------
__global__ __launch_bounds__(256) void gemm_split(const float* __restrict__ X,
                                                  const float* __restrict__ Hs,
                                                  float* __restrict__ fused) {
    __shared__ float xs[BM][BK + 1];
    __shared__ float hs[BK][H_N];
    const int mtile = blockIdx.x;   // 0..31
    const int ks = blockIdx.y;      // 0..KSPLIT-1
    const int tid = threadIdx.x;
    const int tx = tid & 31;        // col group: cols tx*4 .. tx*4+3
    const int ty = tid >> 5;        // 0..7 : rows ty*8 .. ty*8+7
    const int k0 = ks * KC;
    const int k1 = min(V_N, k0 + KC);
    const int row0 = mtile * BM;

    float acc[8][4] = {};

    for (int kb = k0; kb < k1; kb += BK) {
        {
            int lane8 = tid & 7;
            int r = tid >> 3;  // 0..31
            int kcol = kb + lane8 * 4;
            for (int rr = r; rr < BM; rr += 32) {
                float4 xv = make_float4(0.f, 0.f, 0.f, 0.f);
                if (kcol + 3 < k1) {
                    xv = *reinterpret_cast<const float4*>(
                        X + (long long)(row0 + rr) * V_N + kcol);
                } else {
                    float tmp[4] = {0.f, 0.f, 0.f, 0.f};
                    for (int j = 0; j < 4; ++j)
                        if (kcol + j < k1)
                            tmp[j] = X[(long long)(row0 + rr) * V_N + kcol + j];
                    xv = make_float4(tmp[0], tmp[1], tmp[2], tmp[3]);
                }
                xs[rr][lane8 * 4 + 0] = xv.x;
                xs[rr][lane8 * 4 + 1] = xv.y;
                xs[rr][lane8 * 4 + 2] = xv.z;
                xs[rr][lane8 * 4 + 3] = xv.w;
            }
        }
        {
            int cc = tid & 31;
            int rr = tid >> 5;  // 0..7
            for (int r2 = rr; r2 < BK; r2 += 8) {
                int krow = kb + r2;
                float4 hv = make_float4(0.f, 0.f, 0.f, 0.f);
                if (krow < k1)
                    hv = *reinterpret_cast<const float4*>(
                        Hs + (long long)krow * H_N + cc * 4);
                *reinterpret_cast<float4*>(&hs[r2][cc * 4]) = hv;
            }
        }
        __syncthreads();
#pragma unroll
        for (int kk = 0; kk < BK; ++kk) {
            float4 hv = *reinterpret_cast<const float4*>(&hs[kk][tx * 4]);
#pragma unroll
            for (int i = 0; i < 8; ++i) {
                float xv = xs[ty * 8 + i][kk];
                acc[i][0] += xv * hv.x;
                acc[i][1] += xv * hv.y;
                acc[i][2] += xv * hv.z;
                acc[i][3] += xv * hv.w;
            }
        }
        __syncthreads();
    }

#pragma unroll
    for (int i = 0; i < 8; ++i) {
        int row = row0 + ty * 8 + i;
        float* dst = fused + (long long)row * H_N + tx * 4;
        atomicAdd(dst + 0, acc[i][0]);
        atomicAdd(dst + 1, acc[i][1]);
        atomicAdd(dst + 2, acc[i][2]);
        atomicAdd(dst + 3, acc[i][3]);
    }
}

// ---------------- FC epilogue ----------------
__global__ __launch_bounds__(256) void fc_kernel(const float* __restrict__ fused,
                                                 const float* __restrict__ fcW,
                                                 const float* __restrict__ fcb,
                                                 float* __restrict__ out) {
    int idx = blockIdx.x * blockDim.x + threadIdx.x;
    if (idx >= M_N * O_N) return;
    int row = idx >> 4;
    int o = idx & 15;
    float s = fcb[o];
    const float* f = fused + (long long)row * H_N;
#pragma unroll
    for (int h = 0; h < H_N; ++h) s += f[h] * fcW[h * O_N + o];
    out[idx] = s;
}

extern "C" void kernel_launch(void* const* d_in, const int* in_sizes, int n_in,
                              void* d_out, int out_size, void* d_ws, size_t ws_size,
                              hipStream_t stream) {
    const float* x    = (const float*)d_in[0];
    const int* rows   = (const int*)d_in[1];
    const int* cols   = (const int*)d_in[2];
    const float* vals = (const float*)d_in[3];
    const float* W    = (const float*)d_in[4];
    const float* fcW  = (const float*)d_in[5];
    const float* fcb  = (const float*)d_in[6];
    float* out = (float*)d_out;

    // workspace layout
    float* h_sum      = (float*)d_ws;                         // V*H f32
    float* fused      = h_sum + (size_t)V_N * H_N;            // M*H f32
    int*   count      = (int*)(fused + (size_t)M_N * H_N);    // V
    int*   row_start  = count + V_N;                          // V+1
    int*   cursor     = row_start + V_N + 1;                  // V
    int*   sorted_colp= cursor + V_N;                         // NNZ_T
    float* sorted_val = (float*)(sorted_colp + NNZ_T);        // NNZ_T

    // zero fused + count in one pass (contiguous)
    size_t zero_bytes = ((size_t)M_N * H_N) * sizeof(float) + (size_t)V_N * sizeof(int);
    hipMemsetAsync(fused, 0, zero_bytes, stream);

    hist_kernel<<<(NNZ_T + 255) / 256, 256, 0, stream>>>(rows, count);
    scan_kernel<<<1, 1024, 0, stream>>>(count, row_start, cursor);
    scatter_kernel<<<(NNZ_T + 255) / 256, 256, 0, stream>>>(rows, cols, vals, cursor,
                                                            sorted_colp, sorted_val);
    {
        long long total = (long long)V_N * 32;
        accum_kernel<<<(int)((total + 255) / 256), 256, 0, stream>>>(
            row_start, sorted_colp, sorted_val, W, h_sum);
    }

    dim3 g(M_N / BM, KSPLIT);
    gemm_split<<<g, 256, 0, stream>>>(x, h_sum, fused);

    fc_kernel<<<(M_N * O_N + 255) / 256, 256, 0, stream>>>(fused, fcW, fcb, out);
}